// Round 4
// baseline (166.119 us; speedup 1.0000x reference)
//
#include <hip/hip_runtime.h>
#include <math.h>

// KDE via GEMM trick, v4: single-pass fp16 MFMA, zero prep dispatches.
//   density[i] = (1/M) * sum_j exp2(-C2*sq_ij - log2(M))
//   sq_ij = |x_i|^2 + |d_j|^2 - 2*dot(x_i,d_j)
//
// dot computed as fp16(x).fp16(d) via mfma_f32_16x16x32_f16 (one pass; fp16
// RNE error ~2^-11/term -> ~0.12% density error vs 2% threshold). Norms are
// EXACT fp32, computed in-kernel from the same fp32 loads (x during the A
// prologue, d from the staged LDS values each iter) — no prep kernel, no
// workspace (round-3 evidence: the prep dispatch chain cost ~40 us).
//
// Block = 4 waves, tile 128 rows x 256 cols, grid 64x32 = 2048 blocks.
// A (fp32->fp16 fragments) persistent in registers (16 frags = 64 regs).
// B streamed 32 cols/iter as fp32 through a double-buffered 16 KB LDS chunk
// via global_load_lds (uniform base + lane*16 HW scatter, layout below),
// converted to fp16 fragments after ds_read_b128. 8 iters, 1 barrier each;
// stage(it+1) issued at iter top so the pre-barrier vmcnt(0) drain overlaps
// the whole compute phase. 3 blocks/CU (LDS 33 KB, launch_bounds(256,3)).
//
// Fragment mappings (verified end-to-end in rounds 2/3, dtype-independent):
//   A: lane holds A[m=lane&15][k=(lane>>4)*8+j]
//   B: lane holds B^T row-major: col=lane&15, k=(lane>>4)*8+j
//   C/D: col=lane&15, row=(lane>>4)*4+reg

#define D_DIM 128

typedef _Float16 f16x8 __attribute__((ext_vector_type(8)));
typedef __attribute__((ext_vector_type(4))) float f32x4;

__global__ __launch_bounds__(256, 3)
void kde_f16(const float* __restrict__ x, const float* __restrict__ data,
             float* __restrict__ out, int colGroups, float negLogM) {
    // B double buffer: 2 x 16 regions x 64 lanes x 16 B = 32 KB (fp32).
    // Region f2 = (ct*4 + kc)*2 + h holds, at lane*16: 4 floats
    //   data[colBase + it*32 + ct*16 + r][kc*32 + q*8 + h*4 .. +3]
    __shared__ float shb[2][4096];
    __shared__ float xns[128];

    const int tid  = threadIdx.x;
    const int lane = tid & 63;
    const int w    = tid >> 6;
    const int q    = lane >> 4;        // 0..3
    const int r    = lane & 15;        // 0..15
    const int wh   = w >> 1;           // row half: rows wh*64..+63
    const int wc   = w & 1;            // col tile within 32-col chunk

    const int bid = blockIdx.x;
    const int cg  = bid % colGroups;
    const int rb  = bid / colGroups;
    const int rowBase = rb * 128;
    const int colBase = cg * 256;

    const float C2 = (float)(0.5 / 2.50662827463100050242 * 1.44269504088896340736);
    const float twoC2 = 2.0f * C2;

    // ---- A prologue: load fp32, convert to fp16 frags, exact row norms ----
    f16x8 af[4][4];
#pragma unroll
    for (int ri = 0; ri < 4; ++ri) {
        float nrm = 0.0f;
#pragma unroll
        for (int kc = 0; kc < 4; ++kc) {
            const float* p = &x[(size_t)(rowBase + wh * 64 + ri * 16 + r) * D_DIM + kc * 32 + q * 8];
            const float4 f0 = *(const float4*)p;
            const float4 f1 = *(const float4*)(p + 4);
            nrm = fmaf(f0.x, f0.x, nrm); nrm = fmaf(f0.y, f0.y, nrm);
            nrm = fmaf(f0.z, f0.z, nrm); nrm = fmaf(f0.w, f0.w, nrm);
            nrm = fmaf(f1.x, f1.x, nrm); nrm = fmaf(f1.y, f1.y, nrm);
            nrm = fmaf(f1.z, f1.z, nrm); nrm = fmaf(f1.w, f1.w, nrm);
            f16x8 a;
            a[0] = (_Float16)f0.x; a[1] = (_Float16)f0.y;
            a[2] = (_Float16)f0.z; a[3] = (_Float16)f0.w;
            a[4] = (_Float16)f1.x; a[5] = (_Float16)f1.y;
            a[6] = (_Float16)f1.z; a[7] = (_Float16)f1.w;
            af[ri][kc] = a;
        }
        // reduce over the 4 q-groups -> full |x_row|^2 on every lane
        nrm += __shfl_xor(nrm, 16, 64);
        nrm += __shfl_xor(nrm, 32, 64);
        if (q == 0) xns[wh * 64 + ri * 16 + r] = nrm;  // waves 0/1 (and 2/3) dup-write same value
    }

    // B stage: 16 glds issues per chunk, 4 per wave. Uniform LDS base;
    // HW scatters lane i -> base + i*16.
    auto stageB = [&](int nit, int buf) {
#pragma unroll
        for (int i = 0; i < 4; ++i) {
            const int f2 = w * 4 + i;
            const int ct = f2 >> 3, kc = (f2 >> 1) & 3, h = f2 & 1;
            const float* g = &data[(size_t)(colBase + nit * 32 + ct * 16 + r) * D_DIM
                                   + kc * 32 + q * 8 + h * 4];
            __builtin_amdgcn_global_load_lds(
                (const __attribute__((address_space(1))) void*)g,
                (__attribute__((address_space(3))) void*)&shb[buf][f2 * 256], 16, 0, 0);
        }
    };

    stageB(0, 0);
    __syncthreads();   // drains stage(0) + xns writes

    // Per-lane row constants: u = -C2*|x_row|^2 - log2(M) for the 16 rows
    // this lane's accumulators cover (C/D: row = q*4 + p within tile).
    float u[4][4];
#pragma unroll
    for (int ri = 0; ri < 4; ++ri)
#pragma unroll
        for (int p = 0; p < 4; ++p)
            u[ri][p] = fmaf(-C2, xns[wh * 64 + ri * 16 + q * 4 + p], negLogM);

    float srow[4][4];
#pragma unroll
    for (int ri = 0; ri < 4; ++ri)
#pragma unroll
        for (int p = 0; p < 4; ++p) srow[ri][p] = 0.0f;

    const int NIT = 8;   // 256 cols / 32
    for (int it = 0; it < NIT; ++it) {
        const int cur = it & 1;
        if (it + 1 < NIT) stageB(it + 1, cur ^ 1);   // in flight across this iter

        // B fragments (this wave's ct = wc) + exact fp32 col norm.
        f16x8 bf[4];
        float cn = 0.0f;
#pragma unroll
        for (int kc = 0; kc < 4; ++kc) {
            const int f2 = (wc * 4 + kc) * 2;
            const float4 b0 = *(const float4*)&shb[cur][f2 * 256 + lane * 4];
            const float4 b1 = *(const float4*)&shb[cur][(f2 + 1) * 256 + lane * 4];
            cn = fmaf(b0.x, b0.x, cn); cn = fmaf(b0.y, b0.y, cn);
            cn = fmaf(b0.z, b0.z, cn); cn = fmaf(b0.w, b0.w, cn);
            cn = fmaf(b1.x, b1.x, cn); cn = fmaf(b1.y, b1.y, cn);
            cn = fmaf(b1.z, b1.z, cn); cn = fmaf(b1.w, b1.w, cn);
            f16x8 b;
            b[0] = (_Float16)b0.x; b[1] = (_Float16)b0.y;
            b[2] = (_Float16)b0.z; b[3] = (_Float16)b0.w;
            b[4] = (_Float16)b1.x; b[5] = (_Float16)b1.y;
            b[6] = (_Float16)b1.z; b[7] = (_Float16)b1.w;
            bf[kc] = b;
        }
        cn += __shfl_xor(cn, 16, 64);
        cn += __shfl_xor(cn, 32, 64);           // full |d_col|^2, col = ct*16+r
        const float dnv = -C2 * cn;

        f32x4 acc[4];
#pragma unroll
        for (int ri = 0; ri < 4; ++ri) acc[ri] = (f32x4){0.f, 0.f, 0.f, 0.f};
#pragma unroll
        for (int kc = 0; kc < 4; ++kc)
#pragma unroll
            for (int ri = 0; ri < 4; ++ri)
                acc[ri] = __builtin_amdgcn_mfma_f32_16x16x32_f16(af[ri][kc], bf[kc], acc[ri], 0, 0, 0);

#pragma unroll
        for (int ri = 0; ri < 4; ++ri) {
            const float t0 = u[ri][0] + dnv, t1 = u[ri][1] + dnv;
            const float t2 = u[ri][2] + dnv, t3 = u[ri][3] + dnv;
            srow[ri][0] += __builtin_amdgcn_exp2f(fmaf(twoC2, acc[ri][0], t0));
            srow[ri][1] += __builtin_amdgcn_exp2f(fmaf(twoC2, acc[ri][1], t1));
            srow[ri][2] += __builtin_amdgcn_exp2f(fmaf(twoC2, acc[ri][2], t2));
            srow[ri][3] += __builtin_amdgcn_exp2f(fmaf(twoC2, acc[ri][3], t3));
        }

        if (it + 1 < NIT) __syncthreads();  // drains stage(it+1); protects buf reuse
    }

    // Reduce each srow over the 16 col-lanes (r) and accumulate to out.
#pragma unroll
    for (int ri = 0; ri < 4; ++ri)
#pragma unroll
        for (int p = 0; p < 4; ++p) {
            float s = srow[ri][p];
            s += __shfl_xor(s, 1, 64);
            s += __shfl_xor(s, 2, 64);
            s += __shfl_xor(s, 4, 64);
            s += __shfl_xor(s, 8, 64);
            if (r == 0)
                atomicAdd(&out[rowBase + wh * 64 + ri * 16 + q * 4 + p], s);
        }
}

// ---------------- fallback: round-1 VALU kernel (any size, no ws) ---------
#define BN 128
#define BM 128
#define KT 32
#define LDSS 132

__global__ __launch_bounds__(256, 4)
void kde_valu(const float* __restrict__ x, const float* __restrict__ data,
              float* __restrict__ out, int N, int M) {
    __shared__ float xs[KT][LDSS];
    __shared__ float dsh[KT][LDSS];
    __shared__ float xn_s[BN];
    __shared__ float dn_s[BM];
    const int tid = threadIdx.x;
    const int ty = tid >> 4, tx = tid & 15;
    const int rowBase = blockIdx.y * BN, colBase = blockIdx.x * BM;
    float acc[8][8];
#pragma unroll
    for (int i = 0; i < 8; ++i)
#pragma unroll
        for (int j = 0; j < 8; ++j) acc[i][j] = 0.0f;
    float normAcc = 0.0f;
    for (int kc = 0; kc < D_DIM; kc += KT) {
        __syncthreads();
#pragma unroll
        for (int i = 0; i < 4; ++i) {
            const int idx = tid + i * 256;
            const int row = idx >> 3, kq = idx & 7;
            const float4 v = *(const float4*)&x[(size_t)(rowBase + row) * D_DIM + kc + kq * 4];
            xs[kq * 4 + 0][row] = v.x; xs[kq * 4 + 1][row] = v.y;
            xs[kq * 4 + 2][row] = v.z; xs[kq * 4 + 3][row] = v.w;
            const float4 wv = *(const float4*)&data[(size_t)(colBase + row) * D_DIM + kc + kq * 4];
            dsh[kq * 4 + 0][row] = wv.x; dsh[kq * 4 + 1][row] = wv.y;
            dsh[kq * 4 + 2][row] = wv.z; dsh[kq * 4 + 3][row] = wv.w;
        }
        __syncthreads();
        {
            const float* col = (tid < 128) ? &xs[0][tid] : &dsh[0][tid - 128];
#pragma unroll
            for (int k = 0; k < KT; ++k) { const float v = col[k * LDSS]; normAcc = fmaf(v, v, normAcc); }
        }
#pragma unroll
        for (int k = 0; k < KT; ++k) {
            float a[8], b[8];
            *(float4*)&a[0] = *(const float4*)&xs[k][ty * 8];
            *(float4*)&a[4] = *(const float4*)&xs[k][ty * 8 + 4];
            *(float4*)&b[0] = *(const float4*)&dsh[k][tx * 4];
            *(float4*)&b[4] = *(const float4*)&dsh[k][64 + tx * 4];
#pragma unroll
            for (int i = 0; i < 8; ++i)
#pragma unroll
                for (int j = 0; j < 8; ++j) acc[i][j] = fmaf(a[i], b[j], acc[i][j]);
        }
    }
    if (tid < 128) xn_s[tid] = normAcc; else dn_s[tid - 128] = normAcc;
    __syncthreads();
    const float C2 = (float)(0.5 / 2.50662827463100050242 * 1.44269504088896340736);
    const float negLogM = -log2f((float)M);
#pragma unroll
    for (int i = 0; i < 8; ++i) {
        const int row = ty * 8 + i;
        const float xnr = xn_s[row];
        float s = 0.0f;
#pragma unroll
        for (int j = 0; j < 8; ++j) {
            const int col = (j < 4) ? (tx * 4 + j) : (64 + tx * 4 + (j - 4));
            const float sq = xnr + dn_s[col] - 2.0f * acc[i][j];
            s += exp2f(fmaf(-C2, sq, negLogM));
        }
#pragma unroll
        for (int off = 1; off < 16; off <<= 1) s += __shfl_xor(s, off, 64);
        if (tx == 0) atomicAdd(&out[rowBase + row], s);
    }
}

extern "C" void kernel_launch(void* const* d_in, const int* in_sizes, int n_in,
                              void* d_out, int out_size, void* d_ws, size_t ws_size,
                              hipStream_t stream) {
    const float* x    = (const float*)d_in[0];
    const float* data = (const float*)d_in[1];
    float* out = (float*)d_out;
    const int N = in_sizes[0] / D_DIM;
    const int M = in_sizes[1] / D_DIM;

    hipMemsetAsync(d_out, 0, (size_t)out_size * sizeof(float), stream);

    if ((N & 127) || (M & 255)) {
        dim3 grid(M / BM, N / BN);
        kde_valu<<<grid, 256, 0, stream>>>(x, data, out, N, M);
        return;
    }

    const int colGroups = M / 256;
    const int rowBlocks = N / 128;
    kde_f16<<<rowBlocks * colGroups, 256, 0, stream>>>(x, data, out,
                                                       colGroups, -log2f((float)M));
}

// Round 5
// 139.231 us; speedup vs baseline: 1.1931x; 1.1931x over previous
//
#include <hip/hip_runtime.h>
#include <math.h>

// KDE via GEMM trick, v5: single-pass fp16 MFMA, A routed through LDS.
//   density[i] = (1/M) * sum_j exp2(-C2*sq_ij - log2(M))
//   sq_ij = |x_i|^2 + |d_j|^2 - 2*dot(x_i,d_j)
//
// fp16(x).fp16(d) via mfma_f32_16x16x32_f16 (accuracy verified r4: absmax
// 2.8e-17 vs 2.4e-16 threshold). Norms exact fp32, in-kernel, no prep.
//
// ROUND-4 LESSON (counters: WRITE_SIZE 166 MB, FETCH 102 MB = scratch
// spill): __launch_bounds__(256,3) capped the unified VGPR+AGPR budget at
// ~170 while ~190 regs were live -> allocator spilled the loop state.
// Fix: (256,2) (r3-proven no-spill at ~250 live regs) and A-fragments
// produced by ds_read_b128 (compiler's proven ds_read->AGPR path) instead
// of long-lived VALU-converted values.
//
// Structure: block = 4 waves, tile 128 rows x 256 cols, grid 2048.
// Prologue: block converts x-tile fp32->fp16 into LDS (fragment-major,
// 32 KB) + exact row norms; each wave ds_reads its 16 A-frags once; the
// A region is then REUSED as the B double buffer (2 x 16 KB, fp32).
// B streamed 32 cols/iter via global_load_lds, converted to fp16 in regs,
// exact col norms from the same fp32 values. 1 barrier/iter; stage(it+1)
// issued at iter top so the pre-barrier vmcnt(0) drain overlaps compute.
//
// Fragment mappings (verified end-to-end rounds 2-4):
//   A: lane holds A[m=lane&15][k=(lane>>4)*8+j]
//   B: lane holds B^T row-major: col=lane&15, k=(lane>>4)*8+j
//   C/D: col=lane&15, row=(lane>>4)*4+reg

#define D_DIM 128

typedef _Float16 f16x8 __attribute__((ext_vector_type(8)));
typedef __attribute__((ext_vector_type(4))) float f32x4;

__global__ __launch_bounds__(256, 2)
void kde_f16v5(const float* __restrict__ x, const float* __restrict__ data,
               float* __restrict__ out, int colGroups, float negLogM) {
    // 32 KB: first holds A fp16 frags (frag f = t*4+kc, t=0..7 row-tiles,
    // 64 lanes x 16 B); after A is consumed, becomes the B fp32 dbuf
    // (shb[buf][f2*256 + lane*4], f2 = (ct*4+kc)*2+h).
    __shared__ float shb[2][4096];
    __shared__ float xns[128];   // fma(-C2, |x_row|^2, negLogM)

    const int tid  = threadIdx.x;
    const int lane = tid & 63;
    const int w    = tid >> 6;
    const int q    = lane >> 4;        // 0..3
    const int r    = lane & 15;        // 0..15
    const int wh   = w >> 1;           // row half (64 rows)
    const int wc   = w & 1;            // col tile within 32-col chunk

    const int bid = blockIdx.x;
    const int cg  = bid % colGroups;
    const int rb  = bid / colGroups;
    const int rowBase = rb * 128;
    const int colBase = cg * 256;

    const float C2 = (float)(0.5 / 2.50662827463100050242 * 1.44269504088896340736);
    const float twoC2 = 2.0f * C2;

    unsigned short* aptr = (unsigned short*)&shb[0][0];

    // ---- Prologue: x fp32 -> fp16 LDS frags + exact row norms ----
    {
        const int row  = tid >> 1;     // 0..127
        const int half = tid & 1;      // k 0..63 / 64..127
        const float* xp = &x[(size_t)(rowBase + row) * D_DIM + half * 64];
        const int t = row >> 4;
        const int rr = row & 15;
        float nrm = 0.0f;
#pragma unroll
        for (int kc2 = 0; kc2 < 2; ++kc2) {
            float4 v[8];
#pragma unroll
            for (int j = 0; j < 8; ++j) v[j] = *(const float4*)&xp[kc2 * 32 + j * 4];
#pragma unroll
            for (int j = 0; j < 8; ++j) {
                nrm = fmaf(v[j].x, v[j].x, nrm); nrm = fmaf(v[j].y, v[j].y, nrm);
                nrm = fmaf(v[j].z, v[j].z, nrm); nrm = fmaf(v[j].w, v[j].w, nrm);
            }
            const int f = t * 4 + half * 2 + kc2;
#pragma unroll
            for (int qq = 0; qq < 4; ++qq) {
                f16x8 a;
                a[0] = (_Float16)v[2 * qq].x; a[1] = (_Float16)v[2 * qq].y;
                a[2] = (_Float16)v[2 * qq].z; a[3] = (_Float16)v[2 * qq].w;
                a[4] = (_Float16)v[2 * qq + 1].x; a[5] = (_Float16)v[2 * qq + 1].y;
                a[6] = (_Float16)v[2 * qq + 1].z; a[7] = (_Float16)v[2 * qq + 1].w;
                *(f16x8*)&aptr[(size_t)f * 512 + (qq * 16 + rr) * 8] = a;
            }
        }
        nrm += __shfl_xor(nrm, 1, 64);          // combine the two k-halves
        if (half == 0) xns[row] = fmaf(-C2, nrm, negLogM);
    }
    __syncthreads();

    // ---- A fragments (once) + per-lane row constants ----
    f16x8 af[4][4];
#pragma unroll
    for (int ri = 0; ri < 4; ++ri)
#pragma unroll
        for (int kc = 0; kc < 4; ++kc)
            af[ri][kc] = *(const f16x8*)&aptr[(size_t)((wh * 4 + ri) * 4 + kc) * 512 + lane * 8];

    float u[4][4];
#pragma unroll
    for (int ri = 0; ri < 4; ++ri) {
        const f32x4 u4 = *(const f32x4*)&xns[wh * 64 + ri * 16 + q * 4];
        u[ri][0] = u4[0]; u[ri][1] = u4[1]; u[ri][2] = u4[2]; u[ri][3] = u4[3];
    }
    __syncthreads();   // A region free for B staging

    // B stage: 16 glds per chunk, 4 per wave; uniform base + lane*16 scatter.
    auto stageB = [&](int nit, int buf) {
#pragma unroll
        for (int i = 0; i < 4; ++i) {
            const int f2 = w * 4 + i;
            const int ct = f2 >> 3, kc = (f2 >> 1) & 3, h = f2 & 1;
            const float* g = &data[(size_t)(colBase + nit * 32 + ct * 16 + r) * D_DIM
                                   + kc * 32 + q * 8 + h * 4];
            __builtin_amdgcn_global_load_lds(
                (const __attribute__((address_space(1))) void*)g,
                (__attribute__((address_space(3))) void*)&shb[buf][f2 * 256], 16, 0, 0);
        }
    };

    stageB(0, 0);
    __syncthreads();   // drains stage(0)

    float srow[4][4];
#pragma unroll
    for (int ri = 0; ri < 4; ++ri)
#pragma unroll
        for (int p = 0; p < 4; ++p) srow[ri][p] = 0.0f;

    const int NIT = 8;   // 256 cols / 32
    for (int it = 0; it < NIT; ++it) {
        const int cur = it & 1;
        if (it + 1 < NIT) stageB(it + 1, cur ^ 1);   // in flight across this iter

        // B fragments for this wave's col tile (ct = wc) + exact col norm.
        f16x8 bf[4];
        float cn = 0.0f;
#pragma unroll
        for (int kc = 0; kc < 4; ++kc) {
            const int f2 = (wc * 4 + kc) * 2;
            const float4 b0 = *(const float4*)&shb[cur][f2 * 256 + lane * 4];
            const float4 b1 = *(const float4*)&shb[cur][(f2 + 1) * 256 + lane * 4];
            cn = fmaf(b0.x, b0.x, cn); cn = fmaf(b0.y, b0.y, cn);
            cn = fmaf(b0.z, b0.z, cn); cn = fmaf(b0.w, b0.w, cn);
            cn = fmaf(b1.x, b1.x, cn); cn = fmaf(b1.y, b1.y, cn);
            cn = fmaf(b1.z, b1.z, cn); cn = fmaf(b1.w, b1.w, cn);
            f16x8 b;
            b[0] = (_Float16)b0.x; b[1] = (_Float16)b0.y;
            b[2] = (_Float16)b0.z; b[3] = (_Float16)b0.w;
            b[4] = (_Float16)b1.x; b[5] = (_Float16)b1.y;
            b[6] = (_Float16)b1.z; b[7] = (_Float16)b1.w;
            bf[kc] = b;
        }
        cn += __shfl_xor(cn, 16, 64);
        cn += __shfl_xor(cn, 32, 64);           // full |d_col|^2, col = wc*16+r
        const float dnv = -C2 * cn;

        f32x4 acc[4];
#pragma unroll
        for (int ri = 0; ri < 4; ++ri) acc[ri] = (f32x4){0.f, 0.f, 0.f, 0.f};
#pragma unroll
        for (int kc = 0; kc < 4; ++kc)
#pragma unroll
            for (int ri = 0; ri < 4; ++ri)
                acc[ri] = __builtin_amdgcn_mfma_f32_16x16x32_f16(af[ri][kc], bf[kc], acc[ri], 0, 0, 0);

#pragma unroll
        for (int ri = 0; ri < 4; ++ri) {
            const float t0 = u[ri][0] + dnv, t1 = u[ri][1] + dnv;
            const float t2 = u[ri][2] + dnv, t3 = u[ri][3] + dnv;
            srow[ri][0] += __builtin_amdgcn_exp2f(fmaf(twoC2, acc[ri][0], t0));
            srow[ri][1] += __builtin_amdgcn_exp2f(fmaf(twoC2, acc[ri][1], t1));
            srow[ri][2] += __builtin_amdgcn_exp2f(fmaf(twoC2, acc[ri][2], t2));
            srow[ri][3] += __builtin_amdgcn_exp2f(fmaf(twoC2, acc[ri][3], t3));
        }

        if (it + 1 < NIT) __syncthreads();  // drains stage(it+1); protects buffers
    }

    // Reduce each srow over the 16 col-lanes (r) and accumulate to out.
#pragma unroll
    for (int ri = 0; ri < 4; ++ri)
#pragma unroll
        for (int p = 0; p < 4; ++p) {
            float s = srow[ri][p];
            s += __shfl_xor(s, 1, 64);
            s += __shfl_xor(s, 2, 64);
            s += __shfl_xor(s, 4, 64);
            s += __shfl_xor(s, 8, 64);
            if (r == 0)
                atomicAdd(&out[rowBase + wh * 64 + ri * 16 + q * 4 + p], s);
        }
}

// ---------------- fallback: round-1 VALU kernel (any size, no ws) ---------
#define BN 128
#define BM 128
#define KT 32
#define LDSS 132

__global__ __launch_bounds__(256, 4)
void kde_valu(const float* __restrict__ x, const float* __restrict__ data,
              float* __restrict__ out, int N, int M) {
    __shared__ float xs[KT][LDSS];
    __shared__ float dsh[KT][LDSS];
    __shared__ float xn_s[BN];
    __shared__ float dn_s[BM];
    const int tid = threadIdx.x;
    const int ty = tid >> 4, tx = tid & 15;
    const int rowBase = blockIdx.y * BN, colBase = blockIdx.x * BM;
    float acc[8][8];
#pragma unroll
    for (int i = 0; i < 8; ++i)
#pragma unroll
        for (int j = 0; j < 8; ++j) acc[i][j] = 0.0f;
    float normAcc = 0.0f;
    for (int kc = 0; kc < D_DIM; kc += KT) {
        __syncthreads();
#pragma unroll
        for (int i = 0; i < 4; ++i) {
            const int idx = tid + i * 256;
            const int row = idx >> 3, kq = idx & 7;
            const float4 v = *(const float4*)&x[(size_t)(rowBase + row) * D_DIM + kc + kq * 4];
            xs[kq * 4 + 0][row] = v.x; xs[kq * 4 + 1][row] = v.y;
            xs[kq * 4 + 2][row] = v.z; xs[kq * 4 + 3][row] = v.w;
            const float4 wv = *(const float4*)&data[(size_t)(colBase + row) * D_DIM + kc + kq * 4];
            dsh[kq * 4 + 0][row] = wv.x; dsh[kq * 4 + 1][row] = wv.y;
            dsh[kq * 4 + 2][row] = wv.z; dsh[kq * 4 + 3][row] = wv.w;
        }
        __syncthreads();
        {
            const float* col = (tid < 128) ? &xs[0][tid] : &dsh[0][tid - 128];
#pragma unroll
            for (int k = 0; k < KT; ++k) { const float v = col[k * LDSS]; normAcc = fmaf(v, v, normAcc); }
        }
#pragma unroll
        for (int k = 0; k < KT; ++k) {
            float a[8], b[8];
            *(float4*)&a[0] = *(const float4*)&xs[k][ty * 8];
            *(float4*)&a[4] = *(const float4*)&xs[k][ty * 8 + 4];
            *(float4*)&b[0] = *(const float4*)&dsh[k][tx * 4];
            *(float4*)&b[4] = *(const float4*)&dsh[k][64 + tx * 4];
#pragma unroll
            for (int i = 0; i < 8; ++i)
#pragma unroll
                for (int j = 0; j < 8; ++j) acc[i][j] = fmaf(a[i], b[j], acc[i][j]);
        }
    }
    if (tid < 128) xn_s[tid] = normAcc; else dn_s[tid - 128] = normAcc;
    __syncthreads();
    const float C2 = (float)(0.5 / 2.50662827463100050242 * 1.44269504088896340736);
    const float negLogM = -log2f((float)M);
#pragma unroll
    for (int i = 0; i < 8; ++i) {
        const int row = ty * 8 + i;
        const float xnr = xn_s[row];
        float s = 0.0f;
#pragma unroll
        for (int j = 0; j < 8; ++j) {
            const int col = (j < 4) ? (tx * 4 + j) : (64 + tx * 4 + (j - 4));
            const float sq = xnr + dn_s[col] - 2.0f * acc[i][j];
            s += exp2f(fmaf(-C2, sq, negLogM));
        }
#pragma unroll
        for (int off = 1; off < 16; off <<= 1) s += __shfl_xor(s, off, 64);
        if (tx == 0) atomicAdd(&out[rowBase + row], s);
    }
}

extern "C" void kernel_launch(void* const* d_in, const int* in_sizes, int n_in,
                              void* d_out, int out_size, void* d_ws, size_t ws_size,
                              hipStream_t stream) {
    const float* x    = (const float*)d_in[0];
    const float* data = (const float*)d_in[1];
    float* out = (float*)d_out;
    const int N = in_sizes[0] / D_DIM;
    const int M = in_sizes[1] / D_DIM;

    hipMemsetAsync(d_out, 0, (size_t)out_size * sizeof(float), stream);

    if ((N & 127) || (M & 255)) {
        dim3 grid(M / BM, N / BN);
        kde_valu<<<grid, 256, 0, stream>>>(x, data, out, N, M);
        return;
    }

    const int colGroups = M / 256;
    const int rowBlocks = N / 128;
    kde_f16v5<<<rowBlocks * colGroups, 256, 0, stream>>>(x, data, out,
                                                         colGroups, -log2f((float)M));
}

// Round 6
// 111.492 us; speedup vs baseline: 1.4900x; 1.2488x over previous
//
#include <hip/hip_runtime.h>
#include <math.h>

// KDE via GEMM trick, v6: prep -> fragment-ready fp16, barrier-free main.
//   density[i] = (1/M) * sum_j exp2(-C2*sq_ij - log2(M))
//   sq_ij = |x_i|^2 + |d_j|^2 - 2*dot(x_i,d_j)
//
// ROUND-5 EVIDENCE: main kernel latency/barrier-bound (MfmaUtil 7.3,
// VALUBusy 24, occupancy 19.6%, barrier every 32-col iter at 2 blocks/CU).
// Also: the ~50 us total-vs-main gap is HARNESS-FIXED (present in r2..r5
// with and without prep) -> prep dispatches are ~free (r3 vs r5: ~4 us).
//
// v6: prep kernel converts x,data fp32 -> fp16 in MFMA-fragment-major
// layout (frag f=(tile*4+kc)*64+lane holds 16 B; every main-kernel load is
// a perfectly coalesced global_load_dwordx4) and emits pre-scaled norms
// (-C2*|d|^2 and fma(-C2,|x|^2,negLogM)). Main kernel: NO LDS, NO
// barriers, NO conversions — A frags persistent (16 loads), B frags
// prefetched one iter ahead into registers, 16 MFMA + fused exp2 epilogue
// per 16-col tile. Waves fully independent; occupancy VGPR-bound only
// ((256,2) cap = 256 regs, ~165 live -> no spill per r4/r5 lesson).
//
// Fragment mappings (verified end-to-end rounds 2-5):
//   A: lane holds A[m=lane&15][k=(lane>>4)*8+j]
//   B: lane holds B^T row-major: col=lane&15, k=(lane>>4)*8+j
//   C/D: col=lane&15, row=(lane>>4)*4+reg
// fp16 single-pass accuracy verified r4/r5: absmax 2.8e-17 vs 2.4e-16 thr.

#define D_DIM 128

typedef _Float16 f16x8 __attribute__((ext_vector_type(8)));
typedef _Float16 f16x4 __attribute__((ext_vector_type(4)));
typedef __attribute__((ext_vector_type(4))) float f32x4;

#define C2F ((float)(0.5 / 2.50662827463100050242 * 1.44269504088896340736))

// ---- prep: fp32 -> fp16 fragment-major + pre-scaled norms ----------------
// Thread (row, seg 0..31) handles 4 consecutive fp32 of one row.
// k = seg*4 -> kc=seg>>3, q=(seg>>1)&3, j0=(seg&1)*4; store 8 B at
// halves offset ((t*4+kc)*64 + q*16 + r)*8 + j0.
__global__ __launch_bounds__(256)
void prep_kernel(const float* __restrict__ x, const float* __restrict__ data,
                 _Float16* __restrict__ xf, _Float16* __restrict__ df,
                 float* __restrict__ xn_u, float* __restrict__ dn_s,
                 int xThreads, float negLogM) {
    const int gid = blockIdx.x * 256 + threadIdx.x;
    const int which = (gid >= xThreads);
    const int id = which ? (gid - xThreads) : gid;
    const int row = id >> 5, seg = id & 31;
    const float* src = which ? data : x;
    _Float16* dst = which ? df : xf;

    const float4 v = *(const float4*)&src[(size_t)row * D_DIM + seg * 4];

    const int t = row >> 4, r = row & 15;
    const int kc = seg >> 3, q = (seg >> 1) & 3, j0 = (seg & 1) * 4;
    f16x4 h;
    h[0] = (_Float16)v.x; h[1] = (_Float16)v.y;
    h[2] = (_Float16)v.z; h[3] = (_Float16)v.w;
    *(f16x4*)&dst[((size_t)(t * 4 + kc) * 64 + q * 16 + r) * 8 + j0] = h;

    float nrm = fmaf(v.x, v.x, fmaf(v.y, v.y, fmaf(v.z, v.z, v.w * v.w)));
#pragma unroll
    for (int off = 1; off < 32; off <<= 1) nrm += __shfl_xor(nrm, off, 64);
    if (seg == 0) {
        if (which) dn_s[row] = -C2F * nrm;
        else       xn_u[row] = fmaf(-C2F, nrm, negLogM);
    }
}

// ---- main: barrier-free, LDS-free fp16 MFMA ------------------------------
// Block = 4 waves, tile 128 rows x 256 cols. Wave w: rows (w>>1)*64,
// col-tiles (w&1)+2*it, it=0..7.
__global__ __launch_bounds__(256, 2)
void kde_f16v6(const _Float16* __restrict__ xf, const _Float16* __restrict__ df,
               const float* __restrict__ xn_u, const float* __restrict__ dn_s,
               float* __restrict__ out, int colGroups) {
    const int tid  = threadIdx.x;
    const int lane = tid & 63;
    const int w    = tid >> 6;
    const int q    = lane >> 4;
    const int r    = lane & 15;
    const int wh   = w >> 1;
    const int wc   = w & 1;

    const int bid = blockIdx.x;
    const int cg  = bid % colGroups;
    const int rb  = bid / colGroups;
    const int rowBase  = rb * 128;
    const int colTile0 = cg * 16;      // global col-tile index base

    const float twoC2 = 2.0f * C2F;

    // A fragments: 16 coalesced dwordx4 loads, once.
    f16x8 af[4][4];
#pragma unroll
    for (int ri = 0; ri < 4; ++ri) {
        const int tG = rb * 8 + wh * 4 + ri;
#pragma unroll
        for (int kc = 0; kc < 4; ++kc)
            af[ri][kc] = *(const f16x8*)&xf[((size_t)(tG * 4 + kc) * 64 + lane) * 8];
    }

    // Row constants for this lane's 16 accumulator rows.
    float u[4][4];
#pragma unroll
    for (int ri = 0; ri < 4; ++ri) {
        const f32x4 u4 = *(const f32x4*)&xn_u[rowBase + wh * 64 + ri * 16 + q * 4];
        u[ri][0] = u4[0]; u[ri][1] = u4[1]; u[ri][2] = u4[2]; u[ri][3] = u4[3];
    }

    float srow[4][4];
#pragma unroll
    for (int ri = 0; ri < 4; ++ri)
#pragma unroll
        for (int p = 0; p < 4; ++p) srow[ri][p] = 0.0f;

    // B double-buffer in registers, one-iter-ahead prefetch.
    f16x8 bf[2][4];
    float dnv[2];
    {
        const int ctG = colTile0 + wc;
#pragma unroll
        for (int kc = 0; kc < 4; ++kc)
            bf[0][kc] = *(const f16x8*)&df[((size_t)(ctG * 4 + kc) * 64 + lane) * 8];
        dnv[0] = dn_s[ctG * 16 + r];
    }

#pragma unroll
    for (int it = 0; it < 8; ++it) {
        const int cur = it & 1;
        if (it < 7) {
            const int ctG = colTile0 + (it + 1) * 2 + wc;
#pragma unroll
            for (int kc = 0; kc < 4; ++kc)
                bf[cur ^ 1][kc] = *(const f16x8*)&df[((size_t)(ctG * 4 + kc) * 64 + lane) * 8];
            dnv[cur ^ 1] = dn_s[ctG * 16 + r];
        }

        f32x4 acc[4];
#pragma unroll
        for (int ri = 0; ri < 4; ++ri) acc[ri] = (f32x4){0.f, 0.f, 0.f, 0.f};
#pragma unroll
        for (int kc = 0; kc < 4; ++kc)
#pragma unroll
            for (int ri = 0; ri < 4; ++ri)
                acc[ri] = __builtin_amdgcn_mfma_f32_16x16x32_f16(af[ri][kc], bf[cur][kc], acc[ri], 0, 0, 0);

        const float d0 = dnv[cur];
#pragma unroll
        for (int ri = 0; ri < 4; ++ri) {
            srow[ri][0] += __builtin_amdgcn_exp2f(fmaf(twoC2, acc[ri][0], u[ri][0] + d0));
            srow[ri][1] += __builtin_amdgcn_exp2f(fmaf(twoC2, acc[ri][1], u[ri][1] + d0));
            srow[ri][2] += __builtin_amdgcn_exp2f(fmaf(twoC2, acc[ri][2], u[ri][2] + d0));
            srow[ri][3] += __builtin_amdgcn_exp2f(fmaf(twoC2, acc[ri][3], u[ri][3] + d0));
        }
    }

    // Reduce srow over the 16 col-lanes (r) and accumulate to out.
#pragma unroll
    for (int ri = 0; ri < 4; ++ri)
#pragma unroll
        for (int p = 0; p < 4; ++p) {
            float s = srow[ri][p];
            s += __shfl_xor(s, 1, 64);
            s += __shfl_xor(s, 2, 64);
            s += __shfl_xor(s, 4, 64);
            s += __shfl_xor(s, 8, 64);
            if (r == 0)
                atomicAdd(&out[rowBase + wh * 64 + ri * 16 + q * 4 + p], s);
        }
}

// ---------------- fallback: round-1 VALU kernel (any size, no ws) ---------
#define BN 128
#define BM 128
#define KT 32
#define LDSS 132

__global__ __launch_bounds__(256, 4)
void kde_valu(const float* __restrict__ x, const float* __restrict__ data,
              float* __restrict__ out, int N, int M) {
    __shared__ float xs[KT][LDSS];
    __shared__ float dsh[KT][LDSS];
    __shared__ float xn_s[BN];
    __shared__ float dn_s[BM];
    const int tid = threadIdx.x;
    const int ty = tid >> 4, tx = tid & 15;
    const int rowBase = blockIdx.y * BN, colBase = blockIdx.x * BM;
    float acc[8][8];
#pragma unroll
    for (int i = 0; i < 8; ++i)
#pragma unroll
        for (int j = 0; j < 8; ++j) acc[i][j] = 0.0f;
    float normAcc = 0.0f;
    for (int kc = 0; kc < D_DIM; kc += KT) {
        __syncthreads();
#pragma unroll
        for (int i = 0; i < 4; ++i) {
            const int idx = tid + i * 256;
            const int row = idx >> 3, kq = idx & 7;
            const float4 v = *(const float4*)&x[(size_t)(rowBase + row) * D_DIM + kc + kq * 4];
            xs[kq * 4 + 0][row] = v.x; xs[kq * 4 + 1][row] = v.y;
            xs[kq * 4 + 2][row] = v.z; xs[kq * 4 + 3][row] = v.w;
            const float4 wv = *(const float4*)&data[(size_t)(colBase + row) * D_DIM + kc + kq * 4];
            dsh[kq * 4 + 0][row] = wv.x; dsh[kq * 4 + 1][row] = wv.y;
            dsh[kq * 4 + 2][row] = wv.z; dsh[kq * 4 + 3][row] = wv.w;
        }
        __syncthreads();
        {
            const float* col = (tid < 128) ? &xs[0][tid] : &dsh[0][tid - 128];
#pragma unroll
            for (int k = 0; k < KT; ++k) { const float v = col[k * LDSS]; normAcc = fmaf(v, v, normAcc); }
        }
#pragma unroll
        for (int k = 0; k < KT; ++k) {
            float a[8], b[8];
            *(float4*)&a[0] = *(const float4*)&xs[k][ty * 8];
            *(float4*)&a[4] = *(const float4*)&xs[k][ty * 8 + 4];
            *(float4*)&b[0] = *(const float4*)&dsh[k][tx * 4];
            *(float4*)&b[4] = *(const float4*)&dsh[k][64 + tx * 4];
#pragma unroll
            for (int i = 0; i < 8; ++i)
#pragma unroll
                for (int j = 0; j < 8; ++j) acc[i][j] = fmaf(a[i], b[j], acc[i][j]);
        }
    }
    if (tid < 128) xn_s[tid] = normAcc; else dn_s[tid - 128] = normAcc;
    __syncthreads();
    const float C2 = C2F;
    const float negLogM = -log2f((float)M);
#pragma unroll
    for (int i = 0; i < 8; ++i) {
        const int row = ty * 8 + i;
        const float xnr = xn_s[row];
        float s = 0.0f;
#pragma unroll
        for (int j = 0; j < 8; ++j) {
            const int col = (j < 4) ? (tx * 4 + j) : (64 + tx * 4 + (j - 4));
            const float sq = xnr + dn_s[col] - 2.0f * acc[i][j];
            s += exp2f(fmaf(-C2, sq, negLogM));
        }
#pragma unroll
        for (int off = 1; off < 16; off <<= 1) s += __shfl_xor(s, off, 64);
        if (tx == 0) atomicAdd(&out[rowBase + row], s);
    }
}

extern "C" void kernel_launch(void* const* d_in, const int* in_sizes, int n_in,
                              void* d_out, int out_size, void* d_ws, size_t ws_size,
                              hipStream_t stream) {
    const float* x    = (const float*)d_in[0];
    const float* data = (const float*)d_in[1];
    float* out = (float*)d_out;
    const int N = in_sizes[0] / D_DIM;
    const int M = in_sizes[1] / D_DIM;

    hipMemsetAsync(d_out, 0, (size_t)out_size * sizeof(float), stream);

    const size_t need = (size_t)(N + M) * D_DIM * 2 + (size_t)(N + M) * 4;
    if (ws_size < need || (N & 127) || (M & 255)) {
        dim3 grid(M / BM, N / BN);
        kde_valu<<<grid, 256, 0, stream>>>(x, data, out, N, M);
        return;
    }

    _Float16* xf = (_Float16*)d_ws;
    _Float16* df = xf + (size_t)N * D_DIM;
    float* xn_u = (float*)(df + (size_t)M * D_DIM);
    float* dn_s = xn_u + N;

    const float negLogM = -log2f((float)M);
    const int xThreads = N * 32;
    const int totThreads = (N + M) * 32;
    prep_kernel<<<totThreads / 256, 256, 0, stream>>>(x, data, xf, df, xn_u, dn_s,
                                                      xThreads, negLogM);

    const int colGroups = M / 256;
    const int rowBlocks = N / 128;
    kde_f16v6<<<rowBlocks * colGroups, 256, 0, stream>>>(xf, df, xn_u, dn_s, out,
                                                         colGroups);
}